// Round 17
// baseline (63.279 us; speedup 1.0000x reference)
//
#include <hip/hip_runtime.h>
#include <math.h>

typedef int   iv4 __attribute__((ext_vector_type(4)));
typedef float fv4 __attribute__((ext_vector_type(4)));

#define WQ_CAP      100352   // LDS bytes: int8 weight table
#define ACC_CAP     50176    // LDS bytes: int8 per-src accumulator half
#define SGB_CAP     1568     // LDS words: sign bitmap half
#define PART_STRIDE 50176    // bytes per partial accumulator in ws
#define NPART       256      // edge-kernel grid (1 block/CU)

// ---------------------------------------------------------------------------
// Float atomic max via sign-split integer atomics (accumulator init = -inf).
// Monotone non-decreasing in float order on both paths; caller sanitizes -0.0.
// ---------------------------------------------------------------------------
__device__ __forceinline__ void atomicMaxF_dev(float* addr, float v) {
    if (v >= 0.0f) {
        atomicMax(reinterpret_cast<int*>(addr), __float_as_int(v));
    } else {
        atomicMin(reinterpret_cast<unsigned int*>(addr), __float_as_uint(v));
    }
}

// Byte-granular signed max in an LDS word via CAS loop (early-exit on read).
__device__ __forceinline__ void ldsMaxI8(unsigned* wordPtr, int byteLane, int val) {
    const unsigned shift = byteLane * 8;
    const unsigned mask = 0xffu << shift;
    unsigned old = *((volatile unsigned*)wordPtr);
    while (true) {
        int cur = (int)(signed char)((old & mask) >> shift);
        if (val <= cur) return;
        unsigned neu = (old & ~mask) |
                       (((unsigned)(unsigned char)(signed char)val) << shift);
        unsigned prev = atomicCAS(wordPtr, old, neu);
        if (prev == old) return;
        old = prev;
    }
}

// ======================= FAST PATH (5 dispatches) ==========================
// P0: bag init; sign bitmap sgb[s]=(lin[s]>=0) via ballot; max|w| -> sc.
__global__ void prep_kernel(const float* __restrict__ feat,
                            const float* __restrict__ W_lin,
                            const float* __restrict__ w,
                            unsigned* __restrict__ sgb,
                            int* __restrict__ sc,
                            float* __restrict__ bagout,
                            int n_src, int n_w, int num_bags) {
    const int i = blockIdx.x * blockDim.x + threadIdx.x;
    if (i < num_bags) bagout[i] = -INFINITY;

    bool pred = false;
    if (i < n_src) {
        float2 f = *reinterpret_cast<const float2*>(feat + 2 * (size_t)i);
        pred = fmaf(f.x, W_lin[0], f.y * W_lin[1]) >= 0.0f;
    }
    unsigned long long b = __ballot(pred);
    const int lane = threadIdx.x & 63;
    if (lane == 0) {
        const int nWords = (n_src + 31) >> 5;
        const int w0 = (i - lane) >> 5;
        if (w0 < nWords) sgb[w0] = (unsigned)b;
        if (w0 + 1 < nWords) sgb[w0 + 1] = (unsigned)(b >> 32);
    }

    float aw = (i < n_w) ? fabsf(w[i]) : 0.0f;
#pragma unroll
    for (int off = 32; off; off >>= 1) aw = fmaxf(aw, __shfl_down(aw, off, 64));
    if (lane == 0) atomicMax(sc, __float_as_int(aw));
    // sc poison (0xAAAAAAAA) is negative -> always loses; replays idempotent.
}

// P0b: quantize weights to int8 ONCE into global wq.
__global__ void quant_kernel(const float* __restrict__ w,
                             const int* __restrict__ sc,
                             signed char* __restrict__ wq, int n_w) {
    int i = blockIdx.x * blockDim.x + threadIdx.x;
    if (i < n_w) {
        float maxab = __int_as_float(sc[0]);
        float inv = (maxab > 0.0f) ? 127.0f / maxab : 0.0f;
        float q = rintf(w[i] * inv);
        q = fminf(127.0f, fmaxf(-127.0f, q));
        wq[i] = (signed char)q;
    }
}

// P1: edge kernel, software-pipelined (prefetch next octet's index streams
// while LDS-processing the current one — hides global latency at the fixed
// 4-waves/SIMD occupancy). Block b: half = b>>7, slice = b&127; pair
// (b, b+128) shares slice AND XCD -> second stream read is an L2 hit.
__global__ __launch_bounds__(1024) void edge_part_kernel(
    const int* __restrict__ esrc, const int* __restrict__ edst,
    const signed char* __restrict__ wq, const unsigned* __restrict__ sgb,
    unsigned char* __restrict__ parts,
    int n_w, int hb, int n_src, int nE) {
    __shared__ unsigned char lwq[WQ_CAP];
    __shared__ unsigned char lacc[ACC_CAP];
    __shared__ unsigned lsgb[SGB_CAP];

    const int tid = threadIdx.x;
    const int b = blockIdx.x;
    const int half = b >> 7;
    const int slice = b & 127;
    const int halfBase = half ? hb : 0;
    const int halfCnt = half ? (n_src - hb) : hb;

    const int nOct = nE >> 3;
    const int per = (nOct + 127) >> 7;
    const int lo = slice * per;
    const int hi = (lo + per < nOct) ? (lo + per) : nOct;

    // ---- issue first octet's loads BEFORE the LDS prologue (hidden there) --
    int o = lo + tid;
    iv4 csa, csb, cda, cdb;
    if (o < hi) {
        const int base = o << 3;
        csa = *reinterpret_cast<const iv4*>(esrc + base);
        csb = *reinterpret_cast<const iv4*>(esrc + base + 4);
        cda = *reinterpret_cast<const iv4*>(edst + base);
        cdb = *reinterpret_cast<const iv4*>(edst + base + 4);
    }

    // ---- prologue: copy wq, init acc, load bitmap half ----
    {
        const int nw16 = (n_w + 15) >> 4;
        const iv4* s16 = reinterpret_cast<const iv4*>(wq);
        iv4* d16 = reinterpret_cast<iv4*>(lwq);
        for (int i = tid; i < nw16; i += 1024) d16[i] = s16[i];
    }
    const int accW = (halfCnt + 3) >> 2;
    for (int i = tid; i < accW; i += 1024)
        reinterpret_cast<unsigned*>(lacc)[i] = 0x80808080u;
    {
        const int w0 = half ? (hb >> 5) : 0;
        const int myW = (halfCnt + 31) >> 5;
        for (int i = tid; i < myW; i += 1024) lsgb[i] = sgb[w0 + i];
    }
    __syncthreads();

    // ---- pipelined main loop ----
    while (o < hi) {
        const int on = o + 1024;
        iv4 nsa, nsb, nda, ndb;
        if (on < hi) {  // prefetch next octet (loads in flight during LDS work)
            const int nb = on << 3;
            nsa = *reinterpret_cast<const iv4*>(esrc + nb);
            nsb = *reinterpret_cast<const iv4*>(esrc + nb + 4);
            nda = *reinterpret_cast<const iv4*>(edst + nb);
            ndb = *reinterpret_cast<const iv4*>(edst + nb + 4);
        }

        // process current octet: batched compute phase, then CAS phase
        int ss[8] = {csa.x, csa.y, csa.z, csa.w, csb.x, csb.y, csb.z, csb.w};
        int dd[8] = {cda.x, cda.y, cda.z, cda.w, cdb.x, cdb.y, cdb.z, cdb.w};
        unsigned u[8];
        int val[8];
        bool ok[8];
#pragma unroll
        for (int k = 0; k < 8; ++k) {
            u[k] = (unsigned)(ss[k] - halfBase);
            ok[k] = u[k] < (unsigned)halfCnt;
            unsigned uc = ok[k] ? u[k] : 0u;
            int wv = (int)(signed char)lwq[dd[k]];        // always in-bounds
            int sg = (lsgb[uc >> 5] >> (uc & 31)) & 1;
            val[k] = sg ? wv : -wv;
        }
#pragma unroll
        for (int k = 0; k < 8; ++k) {
            if (ok[k])
                ldsMaxI8(reinterpret_cast<unsigned*>(lacc) + (u[k] >> 2),
                         u[k] & 3, val[k]);
        }

        csa = nsa; csb = nsb; cda = nda; cdb = ndb;
        o = on;
    }

    // tail (< 8 edges): last slice's blocks (both halves)
    if (slice == 127) {
        const int i = (nOct << 3) + tid;
        if (i < nE) {
            unsigned u = (unsigned)(esrc[i] - halfBase);
            if (u < (unsigned)halfCnt) {
                int wv = (int)(signed char)lwq[edst[i]];
                int sg = (lsgb[u >> 5] >> (u & 31)) & 1;
                int val = sg ? wv : -wv;
                ldsMaxI8(reinterpret_cast<unsigned*>(lacc) + (u >> 2),
                         u & 3, val);
            }
        }
    }
    __syncthreads();
    // coalesced partial writeback
    unsigned char* dst = parts + (size_t)b * PART_STRIDE;
    for (int i = tid; i < accW; i += 1024)
        reinterpret_cast<unsigned*>(dst)[i] =
            reinterpret_cast<unsigned*>(lacc)[i];
}

// P2: merge — 4 lanes per acc-word (32 partials each, 2-round shfl-xor
// byte-max), then per_src out + bag atomics.
__global__ void merge_kernel(const unsigned char* __restrict__ parts,
                             const float* __restrict__ feat,
                             const float* __restrict__ W_lin,
                             const int* __restrict__ bag_of,
                             const int* __restrict__ sc,
                             float* __restrict__ out,
                             int hb, int n_src, int num_bags) {
    const int wordsPerHalf = ACC_CAP >> 2;
    const int t = blockIdx.x * blockDim.x + threadIdx.x;
    const int T = t >> 2;          // word slot
    const int q = t & 3;           // partial-quarter
    if (T >= 2 * wordsPerHalf) return;
    const int h = (T >= wordsPerHalf) ? 1 : 0;
    const int jw = T - h * wordsPerHalf;
    const int halfBase = h ? hb : 0;
    const int halfCnt = h ? (n_src - hb) : hb;
    const bool live = (jw * 4 < halfCnt);

    int m0 = -128, m1 = -128, m2 = -128, m3 = -128;
    if (live) {
        const unsigned char* base = parts +
            (size_t)(h * 128 + q * 32) * PART_STRIDE + (size_t)jw * 4;
        for (int k = 0; k < 32; ++k) {
            unsigned pw = *reinterpret_cast<const unsigned*>(
                base + (size_t)k * PART_STRIDE);
            int a0 = (int)(signed char)(pw & 0xff);
            int a1 = (int)(signed char)((pw >> 8) & 0xff);
            int a2 = (int)(signed char)((pw >> 16) & 0xff);
            int a3 = (int)(signed char)((pw >> 24) & 0xff);
            m0 = (a0 > m0) ? a0 : m0;
            m1 = (a1 > m1) ? a1 : m1;
            m2 = (a2 > m2) ? a2 : m2;
            m3 = (a3 > m3) ? a3 : m3;
        }
    }
#pragma unroll
    for (int d = 1; d <= 2; d <<= 1) {
        int r0 = __shfl_xor(m0, d, 64);
        int r1 = __shfl_xor(m1, d, 64);
        int r2 = __shfl_xor(m2, d, 64);
        int r3 = __shfl_xor(m3, d, 64);
        m0 = (r0 > m0) ? r0 : m0;
        m1 = (r1 > m1) ? r1 : m1;
        m2 = (r2 > m2) ? r2 : m2;
        m3 = (r3 > m3) ? r3 : m3;
    }
    if (q == 0 && live) {
        const float step = __int_as_float(sc[0]) * (1.0f / 127.0f);
        const float w0 = W_lin[0], w1 = W_lin[1];
        int mm[4] = {m0, m1, m2, m3};
#pragma unroll
        for (int r = 0; r < 4; ++r) {
            const int u = jw * 4 + r;
            if (u < halfCnt) {
                const int s = halfBase + u;
                float2 f = *reinterpret_cast<const float2*>(feat + 2 * (size_t)s);
                float lin = fmaf(f.x, w0, f.y * w1);
                float v = (mm[r] == -128)
                              ? -INFINITY
                              : fabsf(lin) * step * (float)mm[r] + 0.0f;
                out[num_bags + s] = v;
                atomicMaxF_dev(out + bag_of[s], v);
            }
        }
    }
}

// P3: finalize bags: out[b] = v > -10 ? v : 0   (torch init semantics)
__global__ void finalize_kernel(float* __restrict__ bagbuf, int num_bags) {
    int i = blockIdx.x * blockDim.x + threadIdx.x;
    if (i < num_bags) {
        float v = bagbuf[i];
        bagbuf[i] = (v > -10.0f) ? v : 0.0f;
    }
}

// ================== FALLBACK PATH (round-12, 124.9 µs) =====================
__global__ void init_kernel(const float* __restrict__ feat,
                            const float* __restrict__ W_lin,
                            const float* __restrict__ w,
                            float2* __restrict__ snap, float* __restrict__ acc,
                            float* __restrict__ bagbuf, int* __restrict__ sc,
                            int n_src, int n_w, int num_bags) {
    int i = blockIdx.x * blockDim.x + threadIdx.x;
    if (i < n_src) {
        float2 f = *reinterpret_cast<const float2*>(feat + 2 * i);
        snap[i] = make_float2(fmaf(f.x, W_lin[0], f.y * W_lin[1]), -INFINITY);
        acc[i] = -INFINITY;
    }
    if (i < num_bags) bagbuf[i] = -INFINITY;
    float aw = (i < n_w) ? fabsf(w[i]) : 0.0f;
#pragma unroll
    for (int off = 32; off; off >>= 1) aw = fmaxf(aw, __shfl_down(aw, off, 64));
    if ((threadIdx.x & 63) == 0) atomicMax(sc, __float_as_int(aw));
}

template <bool QUANT>
__global__ void edge_fp32_kernel(const int* __restrict__ esrc,
                                 const int* __restrict__ edst,
                                 const float* __restrict__ weights,
                                 const float2* __restrict__ snap,
                                 float* __restrict__ acc,
                                 signed char* __restrict__ wq,
                                 const int* __restrict__ sc, int n_w,
                                 int octLo, int octHi, int nE, int isLast) {
    const int gsz = gridDim.x * blockDim.x;
    const int gid = blockIdx.x * blockDim.x + threadIdx.x;
    if (QUANT) {
        const float maxab = __int_as_float(sc[0]);
        const float inv = (maxab > 0.0f) ? 127.0f / maxab : 0.0f;
        for (int i = gid; i < n_w; i += gsz) {
            float q = rintf(weights[i] * inv);
            q = fminf(127.0f, fmaxf(-127.0f, q));
            wq[i] = (signed char)q;
        }
    }
    const int o = octLo + gid;
    if (o < octHi) {
        const int base = o << 3;
        iv4 sa = *reinterpret_cast<const iv4*>(esrc + base);
        iv4 sb = *reinterpret_cast<const iv4*>(esrc + base + 4);
        iv4 da = *reinterpret_cast<const iv4*>(edst + base);
        iv4 db = *reinterpret_cast<const iv4*>(edst + base + 4);
        int ss[8] = {sa.x, sa.y, sa.z, sa.w, sb.x, sb.y, sb.z, sb.w};
        int dd[8] = {da.x, da.y, da.z, da.w, db.x, db.y, db.z, db.w};
        float w[8];
        float2 p[8];
#pragma unroll
        for (int k = 0; k < 8; ++k) { w[k] = weights[dd[k]]; p[k] = snap[ss[k]]; }
#pragma unroll
        for (int k = 0; k < 8; ++k) {
            float v = w[k] * p[k].x + 0.0f;
            if (v >= p[k].y) atomicMaxF_dev(acc + ss[k], v);
        }
    }
    if (isLast) {
        const int done = (nE >> 3) << 3;
        const int i = done + gid;
        if (i < nE) {
            int s = esrc[i];
            float2 pp = snap[s];
            float v = weights[edst[i]] * pp.x + 0.0f;
            if (v >= pp.y) atomicMaxF_dev(acc + s, v);
        }
    }
}

__global__ void refresh_kernel(float2* __restrict__ snap,
                               const float* __restrict__ acc, int n_src) {
    int i = blockIdx.x * blockDim.x + threadIdx.x;
    if (i < n_src) snap[i].y = acc[i];
}

__global__ __launch_bounds__(1024) void edge_lds_kernel(
    const int* __restrict__ esrc, const int* __restrict__ edst,
    const signed char* __restrict__ wq, const int* __restrict__ sc,
    const float2* __restrict__ snap, float* __restrict__ acc, int n_w,
    int octLo, int octHi, int nE, int isLast) {
    __shared__ signed char lw[WQ_CAP];
    {
        const int nw16 = (n_w + 15) >> 4;
        const iv4* s16 = reinterpret_cast<const iv4*>(wq);
        iv4* d16 = reinterpret_cast<iv4*>(lw);
        for (int i = threadIdx.x; i < nw16; i += blockDim.x) d16[i] = s16[i];
    }
    const float step = __int_as_float(sc[0]) * (1.0f / 127.0f);
    __syncthreads();
    const int gsz = gridDim.x * blockDim.x;
    const int gid = blockIdx.x * blockDim.x + threadIdx.x;
    for (int o = octLo + gid; o < octHi; o += gsz) {
        const int base = o << 3;
        iv4 sa = *reinterpret_cast<const iv4*>(esrc + base);
        iv4 sb = *reinterpret_cast<const iv4*>(esrc + base + 4);
        iv4 da = *reinterpret_cast<const iv4*>(edst + base);
        iv4 db = *reinterpret_cast<const iv4*>(edst + base + 4);
        int ss[8] = {sa.x, sa.y, sa.z, sa.w, sb.x, sb.y, sb.z, sb.w};
        int dd[8] = {da.x, da.y, da.z, da.w, db.x, db.y, db.z, db.w};
        float wv[8];
        float2 p[8];
#pragma unroll
        for (int k = 0; k < 8; ++k) {
            wv[k] = (float)lw[dd[k]];
            p[k] = snap[ss[k]];
        }
#pragma unroll
        for (int k = 0; k < 8; ++k) {
            float v = wv[k] * step * p[k].x + 0.0f;
            if (v >= p[k].y) atomicMaxF_dev(acc + ss[k], v);
        }
    }
    if (isLast) {
        const int done = (nE >> 3) << 3;
        const int i = done + gid;
        if (i < nE) {
            int s = esrc[i];
            float2 pp = snap[s];
            float v = (float)lw[edst[i]] * step * pp.x + 0.0f;
            if (v >= pp.y) atomicMaxF_dev(acc + s, v);
        }
    }
}

__global__ void bag_kernel(const float* __restrict__ acc,
                           const int* __restrict__ bag_of,
                           float* __restrict__ per_src_out,
                           float* __restrict__ bagbuf, int n_src) {
    int i = blockIdx.x * blockDim.x + threadIdx.x;
    if (i < n_src) {
        float m = acc[i];
        per_src_out[i] = m;
        atomicMaxF_dev(bagbuf + bag_of[i], m);
    }
}

// ===========================================================================

extern "C" void kernel_launch(void* const* d_in, const int* in_sizes, int n_in,
                              void* d_out, int out_size, void* d_ws,
                              size_t ws_size, hipStream_t stream) {
    const float* weights = (const float*)d_in[0];
    const float* feat    = (const float*)d_in[1];
    const float* W_lin   = (const float*)d_in[2];
    const int*   esrc    = (const int*)d_in[3];
    const int*   edst    = (const int*)d_in[4];
    const int*   bag_of  = (const int*)d_in[5];

    const int n_w      = in_sizes[0];
    const int n_src    = in_sizes[5];
    const int nE       = in_sizes[3];
    const int num_bags = out_size - n_src;

    float* out    = (float*)d_out;
    float* bagout = out;

    const int TB = 256;
    const int hb = ((n_src / 2) + 31) & ~31;  // 32-aligned half boundary
    const size_t sgbWords = ((size_t)n_src + 31) / 32;
    const size_t needFast = (size_t)NPART * PART_STRIDE +   // parts
                            (size_t)WQ_CAP +                // global wq
                            sgbWords * 4 + 64;              // sgb + sc
    const bool fastOk = (n_w <= WQ_CAP) && (hb <= ACC_CAP) &&
                        ((n_src - hb) <= ACC_CAP) && (n_src > hb) &&
                        (ws_size >= needFast);

    if (fastOk) {
        // ws: [parts 12.84MB][wq 100KB][sgb][sc]
        unsigned char* parts = (unsigned char*)d_ws;
        signed char* wq = (signed char*)(parts + (size_t)NPART * PART_STRIDE);
        unsigned* sgb = (unsigned*)(wq + WQ_CAP);
        int* sc = (int*)(sgb + sgbWords);

        int n = (n_src > n_w) ? n_src : n_w;
        if (num_bags > n) n = num_bags;
        prep_kernel<<<(n + TB - 1) / TB, TB, 0, stream>>>(
            feat, W_lin, weights, sgb, sc, bagout, n_src, n_w, num_bags);

        quant_kernel<<<(n_w + TB - 1) / TB, TB, 0, stream>>>(
            weights, sc, wq, n_w);

        edge_part_kernel<<<NPART, 1024, 0, stream>>>(
            esrc, edst, wq, sgb, parts, n_w, hb, n_src, nE);

        const int mergeThreads = 2 * (ACC_CAP >> 2) * 4;
        merge_kernel<<<(mergeThreads + TB - 1) / TB, TB, 0, stream>>>(
            parts, feat, W_lin, bag_of, sc, out, hb, n_src, num_bags);

        finalize_kernel<<<(num_bags + TB - 1) / TB, TB, 0, stream>>>(
            bagout, num_bags);
        return;
    }

    // ----------------- fallback: round-12 schedule (proven) -----------------
    float* per_src = out + num_bags;
    char* ws = (char*)d_ws;
    float2* snap = (float2*)ws;
    float* acc = (float*)(ws + (size_t)n_src * sizeof(float2));
    signed char* wq = (signed char*)(acc + n_src);
    int* sc = (int*)((char*)wq + (((size_t)n_w + 15) & ~(size_t)15));

    const int nOct = nE >> 3;
    const int c0 = nOct / 16;
    const int c1 = nOct / 4;
    const int refreshBlocks = (n_src + TB - 1) / TB;
    const bool useLds = (n_w + 15) <= WQ_CAP;

    {
        int n = (n_src > num_bags) ? n_src : num_bags;
        if (n_w > n) n = n_w;
        init_kernel<<<(n + TB - 1) / TB, TB, 0, stream>>>(
            feat, W_lin, weights, snap, acc, bagout, sc, n_src, n_w, num_bags);
    }
    if (c0 > 0) {
        int blocks = (c0 + TB - 1) / TB;
        if (useLds)
            edge_fp32_kernel<true><<<blocks, TB, 0, stream>>>(
                esrc, edst, weights, snap, acc, wq, sc, n_w, 0, c0, nE, 0);
        else
            edge_fp32_kernel<false><<<blocks, TB, 0, stream>>>(
                esrc, edst, weights, snap, acc, wq, sc, n_w, 0, c0, nE, 0);
        refresh_kernel<<<refreshBlocks, TB, 0, stream>>>(snap, acc, n_src);
    }
    if (c1 > c0) {
        int blocks = (c1 - c0 + TB - 1) / TB;
        edge_fp32_kernel<false><<<blocks, TB, 0, stream>>>(
            esrc, edst, weights, snap, acc, wq, sc, n_w, c0, c1, nE, 0);
        refresh_kernel<<<refreshBlocks, TB, 0, stream>>>(snap, acc, n_src);
    }
    if (useLds) {
        edge_lds_kernel<<<256, 1024, 0, stream>>>(
            esrc, edst, wq, sc, snap, acc, n_w, c1, nOct, nE, 1);
    } else {
        const int span = nOct - c1;
        int blocks = (span + TB - 1) / TB;
        if (blocks < 1) blocks = 1;
        edge_fp32_kernel<false><<<blocks, TB, 0, stream>>>(
            esrc, edst, weights, snap, acc, wq, sc, n_w, c1, nOct, nE, 1);
    }
    bag_kernel<<<(n_src + TB - 1) / TB, TB, 0, stream>>>(
        acc, bag_of, per_src, bagout, n_src);
    finalize_kernel<<<(num_bags + TB - 1) / TB, TB, 0, stream>>>(
        bagout, num_bags);
}

// Round 18
// 60.704 us; speedup vs baseline: 1.0424x; 1.0424x over previous
//
#include <hip/hip_runtime.h>
#include <math.h>

typedef int   iv4 __attribute__((ext_vector_type(4)));
typedef float fv4 __attribute__((ext_vector_type(4)));

#define WQ_CAP      100352   // LDS bytes: int8 weight table
#define ACC_CAP     50176    // LDS bytes: int8 per-src accumulator half
#define SGB_CAP     1568     // LDS words: sign bitmap half
#define PART_STRIDE 50176    // bytes per partial accumulator in ws
#define NPART       256      // edge-kernel grid (1 block/CU)

// ---------------------------------------------------------------------------
// Float atomic max via sign-split integer atomics (accumulator init = -inf).
// Monotone non-decreasing in float order on both paths; caller sanitizes -0.0.
// ---------------------------------------------------------------------------
__device__ __forceinline__ void atomicMaxF_dev(float* addr, float v) {
    if (v >= 0.0f) {
        atomicMax(reinterpret_cast<int*>(addr), __float_as_int(v));
    } else {
        atomicMin(reinterpret_cast<unsigned int*>(addr), __float_as_uint(v));
    }
}

// Byte-granular signed max in an LDS word via CAS loop (early-exit on read).
__device__ __forceinline__ void ldsMaxI8(unsigned* wordPtr, int byteLane, int val) {
    const unsigned shift = byteLane * 8;
    const unsigned mask = 0xffu << shift;
    unsigned old = *((volatile unsigned*)wordPtr);
    while (true) {
        int cur = (int)(signed char)((old & mask) >> shift);
        if (val <= cur) return;
        unsigned neu = (old & ~mask) |
                       (((unsigned)(unsigned char)(signed char)val) << shift);
        unsigned prev = atomicCAS(wordPtr, old, neu);
        if (prev == old) return;
        old = prev;
    }
}

// ======================= FAST PATH (5 dispatches) ==========================
// P0: bag init; sign bitmap sgb[s]=(lin[s]>=0) via ballot; max|w| -> sc.
__global__ void prep_kernel(const float* __restrict__ feat,
                            const float* __restrict__ W_lin,
                            const float* __restrict__ w,
                            unsigned* __restrict__ sgb,
                            int* __restrict__ sc,
                            float* __restrict__ bagout,
                            int n_src, int n_w, int num_bags) {
    const int i = blockIdx.x * blockDim.x + threadIdx.x;
    if (i < num_bags) bagout[i] = -INFINITY;

    bool pred = false;
    if (i < n_src) {
        float2 f = *reinterpret_cast<const float2*>(feat + 2 * (size_t)i);
        pred = fmaf(f.x, W_lin[0], f.y * W_lin[1]) >= 0.0f;
    }
    unsigned long long b = __ballot(pred);
    const int lane = threadIdx.x & 63;
    if (lane == 0) {
        const int nWords = (n_src + 31) >> 5;
        const int w0 = (i - lane) >> 5;
        if (w0 < nWords) sgb[w0] = (unsigned)b;
        if (w0 + 1 < nWords) sgb[w0 + 1] = (unsigned)(b >> 32);
    }

    float aw = (i < n_w) ? fabsf(w[i]) : 0.0f;
#pragma unroll
    for (int off = 32; off; off >>= 1) aw = fmaxf(aw, __shfl_down(aw, off, 64));
    if (lane == 0) atomicMax(sc, __float_as_int(aw));
    // sc poison (0xAAAAAAAA) is negative -> always loses; replays idempotent.
}

// P0b: quantize weights to int8 ONCE into global wq.
__global__ void quant_kernel(const float* __restrict__ w,
                             const int* __restrict__ sc,
                             signed char* __restrict__ wq, int n_w) {
    int i = blockIdx.x * blockDim.x + threadIdx.x;
    if (i < n_w) {
        float maxab = __int_as_float(sc[0]);
        float inv = (maxab > 0.0f) ? 127.0f / maxab : 0.0f;
        float q = rintf(w[i] * inv);
        q = fminf(127.0f, fmaxf(-127.0f, q));
        wq[i] = (signed char)q;
    }
}

// P1: edge kernel. Block b: half = b>>7 (src range), slice = b&127 (edge
// range). Pair (b, b+128) shares slice AND XCD (128%8==0) -> concurrent
// stream reads hit L2. Prologue: copy wq (100KB int8) + bitmap half into LDS,
// init acc. Per edge: the ENTIRE LDS chain (wq byte, bitmap bit, byte-CAS) is
// predicated on ownership — alien lanes (~50%) issue no LDS requests, halving
// scatter bank pressure and dropping 6.4M wasted byte-reads vs R15.
// M[s] = max(sign(lin[s])*wq[d]); |lin|*step*M = segment max (max/quantize
// commute; error path identical to the proven int8 scheme, absmax ~0.125).
__global__ __launch_bounds__(1024) void edge_part_kernel(
    const int* __restrict__ esrc, const int* __restrict__ edst,
    const signed char* __restrict__ wq, const unsigned* __restrict__ sgb,
    unsigned char* __restrict__ parts,
    int n_w, int hb, int n_src, int nE) {
    __shared__ unsigned char lwq[WQ_CAP];
    __shared__ unsigned char lacc[ACC_CAP];
    __shared__ unsigned lsgb[SGB_CAP];

    const int tid = threadIdx.x;
    const int b = blockIdx.x;
    const int half = b >> 7;
    const int slice = b & 127;
    const int halfBase = half ? hb : 0;
    const int halfCnt = half ? (n_src - hb) : hb;

    // copy int8 weight table (16B vector loads; wq 16B-aligned in ws)
    {
        const int nw16 = (n_w + 15) >> 4;
        const iv4* s16 = reinterpret_cast<const iv4*>(wq);
        iv4* d16 = reinterpret_cast<iv4*>(lwq);
        for (int i = tid; i < nw16; i += 1024) d16[i] = s16[i];
    }
    // acc init to -128
    const int accW = (halfCnt + 3) >> 2;
    for (int i = tid; i < accW; i += 1024)
        reinterpret_cast<unsigned*>(lacc)[i] = 0x80808080u;
    // bitmap half (hb 32-aligned -> clean word slice)
    {
        const int w0 = half ? (hb >> 5) : 0;
        const int myW = (halfCnt + 31) >> 5;
        for (int i = tid; i < myW; i += 1024) lsgb[i] = sgb[w0 + i];
    }
    __syncthreads();

    // edge slice
    const int nOct = nE >> 3;
    const int per = (nOct + 127) >> 7;
    const int lo = slice * per;
    const int hi = (lo + per < nOct) ? (lo + per) : nOct;

    for (int o = lo + tid; o < hi; o += 1024) {
        const int base = o << 3;
        iv4 sa = *reinterpret_cast<const iv4*>(esrc + base);
        iv4 sb = *reinterpret_cast<const iv4*>(esrc + base + 4);
        iv4 da = *reinterpret_cast<const iv4*>(edst + base);
        iv4 db = *reinterpret_cast<const iv4*>(edst + base + 4);
        int ss[8] = {sa.x, sa.y, sa.z, sa.w, sb.x, sb.y, sb.z, sb.w};
        int dd[8] = {da.x, da.y, da.z, da.w, db.x, db.y, db.z, db.w};
#pragma unroll
        for (int k = 0; k < 8; ++k) {
            unsigned u = (unsigned)(ss[k] - halfBase);
            if (u < (unsigned)halfCnt) {   // whole LDS chain predicated
                int wv = (int)(signed char)lwq[dd[k]];
                int sg = (lsgb[u >> 5] >> (u & 31)) & 1;
                int val = sg ? wv : -wv;
                ldsMaxI8(reinterpret_cast<unsigned*>(lacc) + (u >> 2),
                         u & 3, val);
            }
        }
    }
    // tail (< 8 edges): last slice's blocks (both halves)
    if (slice == 127) {
        const int i = (nOct << 3) + tid;
        if (i < nE) {
            unsigned u = (unsigned)(esrc[i] - halfBase);
            if (u < (unsigned)halfCnt) {
                int wv = (int)(signed char)lwq[edst[i]];
                int sg = (lsgb[u >> 5] >> (u & 31)) & 1;
                int val = sg ? wv : -wv;
                ldsMaxI8(reinterpret_cast<unsigned*>(lacc) + (u >> 2),
                         u & 3, val);
            }
        }
    }
    __syncthreads();
    // coalesced partial writeback
    unsigned char* dst = parts + (size_t)b * PART_STRIDE;
    for (int i = tid; i < accW; i += 1024)
        reinterpret_cast<unsigned*>(dst)[i] =
            reinterpret_cast<unsigned*>(lacc)[i];
}

// P2: merge — 4 lanes per acc-word (32 partials each, 2-round shfl-xor
// byte-max), then per_src out + bag atomics.
__global__ void merge_kernel(const unsigned char* __restrict__ parts,
                             const float* __restrict__ feat,
                             const float* __restrict__ W_lin,
                             const int* __restrict__ bag_of,
                             const int* __restrict__ sc,
                             float* __restrict__ out,
                             int hb, int n_src, int num_bags) {
    const int wordsPerHalf = ACC_CAP >> 2;
    const int t = blockIdx.x * blockDim.x + threadIdx.x;
    const int T = t >> 2;          // word slot
    const int q = t & 3;           // partial-quarter
    if (T >= 2 * wordsPerHalf) return;
    const int h = (T >= wordsPerHalf) ? 1 : 0;
    const int jw = T - h * wordsPerHalf;
    const int halfBase = h ? hb : 0;
    const int halfCnt = h ? (n_src - hb) : hb;
    const bool live = (jw * 4 < halfCnt);

    int m0 = -128, m1 = -128, m2 = -128, m3 = -128;
    if (live) {
        const unsigned char* base = parts +
            (size_t)(h * 128 + q * 32) * PART_STRIDE + (size_t)jw * 4;
        for (int k = 0; k < 32; ++k) {
            unsigned pw = *reinterpret_cast<const unsigned*>(
                base + (size_t)k * PART_STRIDE);
            int a0 = (int)(signed char)(pw & 0xff);
            int a1 = (int)(signed char)((pw >> 8) & 0xff);
            int a2 = (int)(signed char)((pw >> 16) & 0xff);
            int a3 = (int)(signed char)((pw >> 24) & 0xff);
            m0 = (a0 > m0) ? a0 : m0;
            m1 = (a1 > m1) ? a1 : m1;
            m2 = (a2 > m2) ? a2 : m2;
            m3 = (a3 > m3) ? a3 : m3;
        }
    }
#pragma unroll
    for (int d = 1; d <= 2; d <<= 1) {
        int r0 = __shfl_xor(m0, d, 64);
        int r1 = __shfl_xor(m1, d, 64);
        int r2 = __shfl_xor(m2, d, 64);
        int r3 = __shfl_xor(m3, d, 64);
        m0 = (r0 > m0) ? r0 : m0;
        m1 = (r1 > m1) ? r1 : m1;
        m2 = (r2 > m2) ? r2 : m2;
        m3 = (r3 > m3) ? r3 : m3;
    }
    if (q == 0 && live) {
        const float step = __int_as_float(sc[0]) * (1.0f / 127.0f);
        const float w0 = W_lin[0], w1 = W_lin[1];
        int mm[4] = {m0, m1, m2, m3};
#pragma unroll
        for (int r = 0; r < 4; ++r) {
            const int u = jw * 4 + r;
            if (u < halfCnt) {
                const int s = halfBase + u;
                float2 f = *reinterpret_cast<const float2*>(feat + 2 * (size_t)s);
                float lin = fmaf(f.x, w0, f.y * w1);
                float v = (mm[r] == -128)
                              ? -INFINITY
                              : fabsf(lin) * step * (float)mm[r] + 0.0f;
                out[num_bags + s] = v;
                atomicMaxF_dev(out + bag_of[s], v);
            }
        }
    }
}

// P3: finalize bags: out[b] = v > -10 ? v : 0   (torch init semantics)
__global__ void finalize_kernel(float* __restrict__ bagbuf, int num_bags) {
    int i = blockIdx.x * blockDim.x + threadIdx.x;
    if (i < num_bags) {
        float v = bagbuf[i];
        bagbuf[i] = (v > -10.0f) ? v : 0.0f;
    }
}

// ================== FALLBACK PATH (round-12, 124.9 µs) =====================
__global__ void init_kernel(const float* __restrict__ feat,
                            const float* __restrict__ W_lin,
                            const float* __restrict__ w,
                            float2* __restrict__ snap, float* __restrict__ acc,
                            float* __restrict__ bagbuf, int* __restrict__ sc,
                            int n_src, int n_w, int num_bags) {
    int i = blockIdx.x * blockDim.x + threadIdx.x;
    if (i < n_src) {
        float2 f = *reinterpret_cast<const float2*>(feat + 2 * i);
        snap[i] = make_float2(fmaf(f.x, W_lin[0], f.y * W_lin[1]), -INFINITY);
        acc[i] = -INFINITY;
    }
    if (i < num_bags) bagbuf[i] = -INFINITY;
    float aw = (i < n_w) ? fabsf(w[i]) : 0.0f;
#pragma unroll
    for (int off = 32; off; off >>= 1) aw = fmaxf(aw, __shfl_down(aw, off, 64));
    if ((threadIdx.x & 63) == 0) atomicMax(sc, __float_as_int(aw));
}

template <bool QUANT>
__global__ void edge_fp32_kernel(const int* __restrict__ esrc,
                                 const int* __restrict__ edst,
                                 const float* __restrict__ weights,
                                 const float2* __restrict__ snap,
                                 float* __restrict__ acc,
                                 signed char* __restrict__ wq,
                                 const int* __restrict__ sc, int n_w,
                                 int octLo, int octHi, int nE, int isLast) {
    const int gsz = gridDim.x * blockDim.x;
    const int gid = blockIdx.x * blockDim.x + threadIdx.x;
    if (QUANT) {
        const float maxab = __int_as_float(sc[0]);
        const float inv = (maxab > 0.0f) ? 127.0f / maxab : 0.0f;
        for (int i = gid; i < n_w; i += gsz) {
            float q = rintf(weights[i] * inv);
            q = fminf(127.0f, fmaxf(-127.0f, q));
            wq[i] = (signed char)q;
        }
    }
    const int o = octLo + gid;
    if (o < octHi) {
        const int base = o << 3;
        iv4 sa = *reinterpret_cast<const iv4*>(esrc + base);
        iv4 sb = *reinterpret_cast<const iv4*>(esrc + base + 4);
        iv4 da = *reinterpret_cast<const iv4*>(edst + base);
        iv4 db = *reinterpret_cast<const iv4*>(edst + base + 4);
        int ss[8] = {sa.x, sa.y, sa.z, sa.w, sb.x, sb.y, sb.z, sb.w};
        int dd[8] = {da.x, da.y, da.z, da.w, db.x, db.y, db.z, db.w};
        float w[8];
        float2 p[8];
#pragma unroll
        for (int k = 0; k < 8; ++k) { w[k] = weights[dd[k]]; p[k] = snap[ss[k]]; }
#pragma unroll
        for (int k = 0; k < 8; ++k) {
            float v = w[k] * p[k].x + 0.0f;
            if (v >= p[k].y) atomicMaxF_dev(acc + ss[k], v);
        }
    }
    if (isLast) {
        const int done = (nE >> 3) << 3;
        const int i = done + gid;
        if (i < nE) {
            int s = esrc[i];
            float2 pp = snap[s];
            float v = weights[edst[i]] * pp.x + 0.0f;
            if (v >= pp.y) atomicMaxF_dev(acc + s, v);
        }
    }
}

__global__ void refresh_kernel(float2* __restrict__ snap,
                               const float* __restrict__ acc, int n_src) {
    int i = blockIdx.x * blockDim.x + threadIdx.x;
    if (i < n_src) snap[i].y = acc[i];
}

__global__ __launch_bounds__(1024) void edge_lds_kernel(
    const int* __restrict__ esrc, const int* __restrict__ edst,
    const signed char* __restrict__ wq, const int* __restrict__ sc,
    const float2* __restrict__ snap, float* __restrict__ acc, int n_w,
    int octLo, int octHi, int nE, int isLast) {
    __shared__ signed char lw[WQ_CAP];
    {
        const int nw16 = (n_w + 15) >> 4;
        const iv4* s16 = reinterpret_cast<const iv4*>(wq);
        iv4* d16 = reinterpret_cast<iv4*>(lw);
        for (int i = threadIdx.x; i < nw16; i += blockDim.x) d16[i] = s16[i];
    }
    const float step = __int_as_float(sc[0]) * (1.0f / 127.0f);
    __syncthreads();
    const int gsz = gridDim.x * blockDim.x;
    const int gid = blockIdx.x * blockDim.x + threadIdx.x;
    for (int o = octLo + gid; o < octHi; o += gsz) {
        const int base = o << 3;
        iv4 sa = *reinterpret_cast<const iv4*>(esrc + base);
        iv4 sb = *reinterpret_cast<const iv4*>(esrc + base + 4);
        iv4 da = *reinterpret_cast<const iv4*>(edst + base);
        iv4 db = *reinterpret_cast<const iv4*>(edst + base + 4);
        int ss[8] = {sa.x, sa.y, sa.z, sa.w, sb.x, sb.y, sb.z, sb.w};
        int dd[8] = {da.x, da.y, da.z, da.w, db.x, db.y, db.z, db.w};
        float wv[8];
        float2 p[8];
#pragma unroll
        for (int k = 0; k < 8; ++k) {
            wv[k] = (float)lw[dd[k]];
            p[k] = snap[ss[k]];
        }
#pragma unroll
        for (int k = 0; k < 8; ++k) {
            float v = wv[k] * step * p[k].x + 0.0f;
            if (v >= p[k].y) atomicMaxF_dev(acc + ss[k], v);
        }
    }
    if (isLast) {
        const int done = (nE >> 3) << 3;
        const int i = done + gid;
        if (i < nE) {
            int s = esrc[i];
            float2 pp = snap[s];
            float v = (float)lw[edst[i]] * step * pp.x + 0.0f;
            if (v >= pp.y) atomicMaxF_dev(acc + s, v);
        }
    }
}

__global__ void bag_kernel(const float* __restrict__ acc,
                           const int* __restrict__ bag_of,
                           float* __restrict__ per_src_out,
                           float* __restrict__ bagbuf, int n_src) {
    int i = blockIdx.x * blockDim.x + threadIdx.x;
    if (i < n_src) {
        float m = acc[i];
        per_src_out[i] = m;
        atomicMaxF_dev(bagbuf + bag_of[i], m);
    }
}

// ===========================================================================

extern "C" void kernel_launch(void* const* d_in, const int* in_sizes, int n_in,
                              void* d_out, int out_size, void* d_ws,
                              size_t ws_size, hipStream_t stream) {
    const float* weights = (const float*)d_in[0];
    const float* feat    = (const float*)d_in[1];
    const float* W_lin   = (const float*)d_in[2];
    const int*   esrc    = (const int*)d_in[3];
    const int*   edst    = (const int*)d_in[4];
    const int*   bag_of  = (const int*)d_in[5];

    const int n_w      = in_sizes[0];
    const int n_src    = in_sizes[5];
    const int nE       = in_sizes[3];
    const int num_bags = out_size - n_src;

    float* out    = (float*)d_out;
    float* bagout = out;

    const int TB = 256;
    const int hb = ((n_src / 2) + 31) & ~31;  // 32-aligned half boundary
    const size_t sgbWords = ((size_t)n_src + 31) / 32;
    const size_t needFast = (size_t)NPART * PART_STRIDE +   // parts
                            (size_t)WQ_CAP +                // global wq
                            sgbWords * 4 + 64;              // sgb + sc
    const bool fastOk = (n_w <= WQ_CAP) && (hb <= ACC_CAP) &&
                        ((n_src - hb) <= ACC_CAP) && (n_src > hb) &&
                        (ws_size >= needFast);

    if (fastOk) {
        // ws: [parts 12.84MB][wq 100KB][sgb][sc]
        unsigned char* parts = (unsigned char*)d_ws;
        signed char* wq = (signed char*)(parts + (size_t)NPART * PART_STRIDE);
        unsigned* sgb = (unsigned*)(wq + WQ_CAP);
        int* sc = (int*)(sgb + sgbWords);

        int n = (n_src > n_w) ? n_src : n_w;
        if (num_bags > n) n = num_bags;
        prep_kernel<<<(n + TB - 1) / TB, TB, 0, stream>>>(
            feat, W_lin, weights, sgb, sc, bagout, n_src, n_w, num_bags);

        quant_kernel<<<(n_w + TB - 1) / TB, TB, 0, stream>>>(
            weights, sc, wq, n_w);

        edge_part_kernel<<<NPART, 1024, 0, stream>>>(
            esrc, edst, wq, sgb, parts, n_w, hb, n_src, nE);

        const int mergeThreads = 2 * (ACC_CAP >> 2) * 4;
        merge_kernel<<<(mergeThreads + TB - 1) / TB, TB, 0, stream>>>(
            parts, feat, W_lin, bag_of, sc, out, hb, n_src, num_bags);

        finalize_kernel<<<(num_bags + TB - 1) / TB, TB, 0, stream>>>(
            bagout, num_bags);
        return;
    }

    // ----------------- fallback: round-12 schedule (proven) -----------------
    float* per_src = out + num_bags;
    char* ws = (char*)d_ws;
    float2* snap = (float2*)ws;
    float* acc = (float*)(ws + (size_t)n_src * sizeof(float2));
    signed char* wq = (signed char*)(acc + n_src);
    int* sc = (int*)((char*)wq + (((size_t)n_w + 15) & ~(size_t)15));

    const int nOct = nE >> 3;
    const int c0 = nOct / 16;
    const int c1 = nOct / 4;
    const int refreshBlocks = (n_src + TB - 1) / TB;
    const bool useLds = (n_w + 15) <= WQ_CAP;

    {
        int n = (n_src > num_bags) ? n_src : num_bags;
        if (n_w > n) n = n_w;
        init_kernel<<<(n + TB - 1) / TB, TB, 0, stream>>>(
            feat, W_lin, weights, snap, acc, bagout, sc, n_src, n_w, num_bags);
    }
    if (c0 > 0) {
        int blocks = (c0 + TB - 1) / TB;
        if (useLds)
            edge_fp32_kernel<true><<<blocks, TB, 0, stream>>>(
                esrc, edst, weights, snap, acc, wq, sc, n_w, 0, c0, nE, 0);
        else
            edge_fp32_kernel<false><<<blocks, TB, 0, stream>>>(
                esrc, edst, weights, snap, acc, wq, sc, n_w, 0, c0, nE, 0);
        refresh_kernel<<<refreshBlocks, TB, 0, stream>>>(snap, acc, n_src);
    }
    if (c1 > c0) {
        int blocks = (c1 - c0 + TB - 1) / TB;
        edge_fp32_kernel<false><<<blocks, TB, 0, stream>>>(
            esrc, edst, weights, snap, acc, wq, sc, n_w, c0, c1, nE, 0);
        refresh_kernel<<<refreshBlocks, TB, 0, stream>>>(snap, acc, n_src);
    }
    if (useLds) {
        edge_lds_kernel<<<256, 1024, 0, stream>>>(
            esrc, edst, wq, sc, snap, acc, n_w, c1, nOct, nE, 1);
    } else {
        const int span = nOct - c1;
        int blocks = (span + TB - 1) / TB;
        if (blocks < 1) blocks = 1;
        edge_fp32_kernel<false><<<blocks, TB, 0, stream>>>(
            esrc, edst, weights, snap, acc, wq, sc, n_w, c1, nOct, nE, 1);
    }
    bag_kernel<<<(n_src + TB - 1) / TB, TB, 0, stream>>>(
        acc, bag_of, per_src, bagout, n_src);
    finalize_kernel<<<(num_bags + TB - 1) / TB, TB, 0, stream>>>(
        bagout, num_bags);
}